// Round 12
// baseline (216.267 us; speedup 1.0000x reference)
//
#include <hip/hip_runtime.h>
#include <hip/hip_bf16.h>

#define FDIM 256
#define F2   128           // bf162 / float2 elements per row
#define CAP  256           // padded CSR row capacity (max degree ~70 << CAP)
#define T_STEPS 8
#define LR_X 0.1f
#define EXT_BIT (1 << 24)

typedef __hip_bfloat162 bf2;

__device__ __forceinline__ float ftanh(float x) {
    float ax = fabsf(x);
    float z  = __expf(-2.f * ax);
    float t  = (1.f - z) * __builtin_amdgcn_rcpf(1.f + z);
    return copysignf(t, x);
}
__device__ __forceinline__ float2 bf22f(const bf2 v) {
    return make_float2(__bfloat162float(v.x), __bfloat162float(v.y));
}
__device__ __forceinline__ bf2 f22bf(float x, float y) {
    bf2 r; r.x = __float2bfloat16(x); r.y = __float2bfloat16(y); return r;
}

// ---- Build (padded CSR: no scan) ------------------------------------------

// Fused: blocks [0,gE) scatter edges into padded rows; blocks [gE,..) init
// vals(d_out)/th2.
__global__ void k_fill_init(const int* __restrict__ src, const int* __restrict__ dst,
                            int* __restrict__ cnt, int* __restrict__ keyT,
                            int* __restrict__ colS, int E, int NI,
                            const float* __restrict__ vin, float* __restrict__ vals,
                            bf2* __restrict__ th2, int NF2, int gE) {
    const int b = (int)blockIdx.x;
    if (b < gE) {
        int e = b * 256 + (int)threadIdx.x;
        if (e < E) {
            int sc = src[e];
            int d  = dst[e];
            int p  = atomicAdd(&cnt[d], 1);       // cnt ends as degree
            if (p < CAP) {
                keyT[d * CAP + p] = ((sc >= NI) ? EXT_BIT : 0) | e;
                colS[d * CAP + p] = sc;
            }
        }
    } else {
        int i = (b - gE) * 256 + (int)threadIdx.x;
        if (i < NF2) {
            float2 v = ((const float2*)vin)[i];
            ((float2*)vals)[i] = v;
            th2[i] = f22bf(ftanh(v.x), ftanh(v.y));
        }
    }
}

// ---- Gather helpers: shfl-broadcast edge loop ------------------------------

__device__ __forceinline__ void gchunk(int c, float ww, int n,
                                       const bf2* __restrict__ t2, int f,
                                       float& ax, float& ay, float& bx, float& by) {
    int j = 0;
    for (; j + 2 <= n; j += 2) {
        const int   c0 = __shfl(c, j),  c1 = __shfl(c, j + 1);
        const float w0 = __shfl(ww, j), w1 = __shfl(ww, j + 1);
        const float2 t0 = bf22f(t2[c0 + f]);
        const float2 t1 = bf22f(t2[c1 + f]);
        ax = fmaf(w0, t0.x, ax); ay = fmaf(w0, t0.y, ay);
        bx = fmaf(w1, t1.x, bx); by = fmaf(w1, t1.y, by);
    }
    if (j < n) {
        const int c0 = __shfl(c, j); const float w0 = __shfl(ww, j);
        const float2 t0 = bf22f(t2[c0 + f]);
        ax = fmaf(w0, t0.x, ax); ay = fmaf(w0, t0.y, ay);
    }
}

// Tail chunks (rare: deg > 64), guarded loads.
__device__ __forceinline__ void gtail(const int2* __restrict__ cw, int rbase,
                                      int s, int e, int lane,
                                      const bf2* __restrict__ t2, int f,
                                      float& ax, float& ay, float& bx, float& by) {
    for (int base = s; base < e; base += 64) {
        const int n = min(64, e - base);
        int c = 0; float ww = 0.f;
        if (lane < n) { int2 p = cw[rbase + base + lane]; c = p.x; ww = __int_as_float(p.y); }
        gchunk(c, ww, n, t2, f, ax, ay, bx, by);
    }
}

// ---- Step 0: fused rank-order + full-row gather ----------------------------
// Per row (128 threads = 2 waves): both waves redundantly rank the row's
// padded slots by key=(is_ext<<24)|eid, write cw (col*F2, w-bits) in order,
// __syncthreads, then gather. cw/nintA persist for steps 1..7 and grad.
__global__ __launch_bounds__(256) void k_pred_first(
    const int* __restrict__ keyT, const int* __restrict__ colS,
    const int* __restrict__ cnt, const float* __restrict__ w,
    int2* __restrict__ cw, int* __restrict__ nintA,
    const float2* __restrict__ vals2, float2* __restrict__ predc2,
    const bf2* __restrict__ th2, float2* __restrict__ err2,
    bf2* __restrict__ dd2, int N, int NI) {
    const int r = (int)blockIdx.x * 2 + ((int)threadIdx.x >> 7);
    if (r >= N) return;
    const int f = (int)threadIdx.x & 127;
    const int lane = (int)threadIdx.x & 63;
    const int rbase = r * CAP;

    // rank + scatter (redundant across the row's 2 waves; same values written)
    const int deg = min(cnt[r], CAP);
    int nint = 0;
    for (int i = lane; i < deg; i += 64) {
        const int myk = keyT[rbase + i];
        int rank = 0;
        for (int j = 0; j < deg; ++j)
            rank += (keyT[rbase + j] < myk) ? 1 : 0;
        const int sc = colS[rbase + i];
        int2 p;
        p.x = sc * F2;
        p.y = __float_as_int(w[(size_t)sc * N + r]);
        cw[rbase + rank] = p;
        nint += (myk < EXT_BIT) ? 1 : 0;
    }
    for (int o = 1; o < 64; o <<= 1) nint += __shfl_xor(nint, o);
    if (lane == 0) nintA[r] = nint;
    __threadfence_block();
    __syncthreads();

    // gather (order identical to the split version)
    const int2 p0 = cw[rbase + lane];          // chunk 0
    float ix = 0.f, iy = 0.f, jx = 0.f, jy = 0.f;   // internal-col part
    gchunk(p0.x, __int_as_float(p0.y), min(64, nint), th2, f, ix, iy, jx, jy);
    gtail(cw, rbase, 64, nint, lane, th2, f, ix, iy, jx, jy);
    float xx = 0.f, xy = 0.f, yx = 0.f, yy = 0.f;   // external-col part
    gtail(cw, rbase, nint, deg, lane, th2, f, xx, xy, yx, yy);

    const int idx = r * F2 + f;
    const float pcx = xx + yx, pcy = xy + yy;
    predc2[idx] = make_float2(pcx, pcy);
    const float2 v = vals2[idx];
    const float ex = v.x - (pcx + ix + jx);
    const float ey = v.y - (pcy + iy + jy);
    if (r < NI) err2[idx] = make_float2(ex, ey);
    const float ux = ftanh(ex), uy = ftanh(ey);
    dd2[idx] = f22bf(1.f - ux * ux, 1.f - uy * uy);
}

// ---- Steps 1..7: internal-col gather + cached predc ------------------------
// Chunk-0 (col,w) pairs loaded SPECULATIVELY (padded row: always in-bounds;
// lanes >= nint never consumed) — 2 dependent global latencies per block.
__global__ __launch_bounds__(256) void k_pred(
    const int* __restrict__ nintA, const int2* __restrict__ cw,
    const float2* __restrict__ vals2, const float2* __restrict__ predc2,
    const bf2* __restrict__ th2, float2* __restrict__ err2,
    bf2* __restrict__ dd2, int N, int NI) {
    const int r = (int)blockIdx.x * 2 + ((int)threadIdx.x >> 7);
    if (r >= N) return;
    const int f = (int)threadIdx.x & 127;
    const int lane = (int)threadIdx.x & 63;
    const int rbase = r * CAP;
    const int2 p0 = cw[rbase + lane];          // speculative chunk 0
    const int ni = nintA[r];
    float ax = 0.f, ay = 0.f, bx = 0.f, by = 0.f;
    gchunk(p0.x, __int_as_float(p0.y), min(64, ni), th2, f, ax, ay, bx, by);
    gtail(cw, rbase, 64, ni, lane, th2, f, ax, ay, bx, by);
    const int idx = r * F2 + f;
    const float2 pc = predc2[idx];
    const float2 v  = vals2[idx];
    const float ex = v.x - (pc.x + ax + bx);
    const float ey = v.y - (pc.y + ay + by);
    if (r < NI) err2[idx] = make_float2(ex, ey);
    const float ux = ftanh(ex), uy = ftanh(ey);
    dd2[idx] = f22bf(1.f - ux * ux, 1.f - uy * uy);
}

// Internal rows: g = sum w_e*dd[col]; vals -= lr*(err-g); th = tanh(vals).
// writeTh=0 on the last step (th dead afterwards).
__global__ __launch_bounds__(256) void k_grad(
    const int* __restrict__ cnt, const int2* __restrict__ cw,
    const float2* __restrict__ err2, const bf2* __restrict__ dd2,
    float2* __restrict__ vals2, bf2* __restrict__ th2, int NI, int writeTh) {
    const int r = (int)blockIdx.x * 2 + ((int)threadIdx.x >> 7);
    if (r >= NI) return;
    const int f = (int)threadIdx.x & 127;
    const int lane = (int)threadIdx.x & 63;
    const int rbase = r * CAP;
    const int2 p0 = cw[rbase + lane];          // speculative chunk 0
    const int de = min(cnt[r], CAP);
    float ax = 0.f, ay = 0.f, bx = 0.f, by = 0.f;
    gchunk(p0.x, __int_as_float(p0.y), min(64, de), dd2, f, ax, ay, bx, by);
    gtail(cw, rbase, 64, de, lane, dd2, f, ax, ay, bx, by);
    const int idx = r * F2 + f;
    const float2 er = err2[idx];
    const float2 v  = vals2[idx];
    const float nx = v.x - LR_X * (er.x - (ax + bx));
    const float ny = v.y - LR_X * (er.y - (ay + by));
    vals2[idx] = make_float2(nx, ny);
    if (writeTh) th2[idx] = f22bf(ftanh(nx), ftanh(ny));
}

// ---- Launch ---------------------------------------------------------------

extern "C" void kernel_launch(void* const* d_in, const int* in_sizes, int n_in,
                              void* d_out, int out_size, void* d_ws, size_t ws_size,
                              hipStream_t stream) {
    const float* values = (const float*)d_in[0];
    const float* w      = (const float*)d_in[1];
    const int*   edge   = (const int*)d_in[2];
    const int NF = in_sizes[0];            // N*F
    const int N  = NF / FDIM;              // 5000
    const int E  = in_sizes[2] / 2;        // 160000
    const int NI = in_sizes[3];            // 2500
    const int NF2 = NF / 2;
    const int* srcp = edge;
    const int* dstp = edge + E;
    float* vals = (float*)d_out;

    char* ws = (char*)d_ws;
    size_t off = 0;
    auto alloc = [&](size_t bytes) {
        void* p = ws + off;
        off = (off + bytes + 255) & ~(size_t)255;
        return p;
    };
    int*  cnt   = (int*) alloc((size_t)N * sizeof(int));
    int*  nintA = (int*) alloc((size_t)N * sizeof(int));
    int*  keyT  = (int*) alloc((size_t)N * CAP * sizeof(int));
    int*  colS  = (int*) alloc((size_t)N * CAP * sizeof(int));
    int2* cw    = (int2*)alloc((size_t)N * CAP * sizeof(int2));
    bf2*  th2   = (bf2*) alloc((size_t)NF2 * sizeof(bf2));
    bf2*  dd2   = (bf2*) alloc((size_t)NF2 * sizeof(bf2));
    float* err   = (float*)alloc((size_t)NF * sizeof(float));
    float* predc = (float*)alloc((size_t)NF * sizeof(float));
    (void)ws_size; (void)n_in; (void)out_size;

    float2* vals2  = (float2*)vals;
    float2* err2   = (float2*)err;
    float2* predc2 = (float2*)predc;

    hipMemsetAsync(cnt, 0, (size_t)N * sizeof(int), stream);
    const int gE   = (E + 255) / 256;
    const int gNF2 = (NF2 + 255) / 256;
    k_fill_init<<<gE + gNF2, 256, 0, stream>>>(srcp, dstp, cnt, keyT, colS, E, NI,
                                               values, vals, th2, NF2, gE);

    const int gP = (N + 1) / 2;
    const int gG = (NI + 1) / 2;
    for (int t = 0; t < T_STEPS; ++t) {
        if (t == 0)
            k_pred_first<<<gP, 256, 0, stream>>>(keyT, colS, cnt, w, cw, nintA,
                                                 vals2, predc2, th2, err2, dd2, N, NI);
        else
            k_pred<<<gP, 256, 0, stream>>>(nintA, cw, vals2, predc2, th2, err2, dd2, N, NI);
        k_grad<<<gG, 256, 0, stream>>>(cnt, cw, err2, dd2, vals2, th2, NI,
                                       (t == T_STEPS - 1) ? 0 : 1);
    }
}